// Round 14
// baseline (138.867 us; speedup 1.0000x reference)
//
#include <hip/hip_runtime.h>

#define N    1024
#define HD   64
#define MD   32
#define BLK  256        // k_p0 block
#define BLKP 512        // pair-kernel block: 8 waves
#define WROW (2 * HD + 1)   // 129, w_msg row stride
#define REPS 8          // DIAGNOSTIC: main-loop replication to force pair
                        // kernels into rocprof top-5 (output scaled back, exact)

// ---------------------------------------------------------------------------
// P0: h0 = feat + posenc; A1/B1 projections. One block per 4 rows.
// ---------------------------------------------------------------------------
__global__ __launch_bounds__(BLK) void k_p0(const float* __restrict__ feat,
                                            const float* __restrict__ wmsg,
                                            const float* __restrict__ bmsg,
                                            float* __restrict__ h0,
                                            float* __restrict__ A,
                                            float* __restrict__ Bb)
{
    __shared__ float scr[4160 + 4 * HD];
    const int tid = threadIdx.x;
    const int n0  = blockIdx.x * 4;

    for (int u = tid; u < MD * WROW; u += BLK) scr[u] = wmsg[u];   // 4128 floats
    float* hrow = scr + 4160;
    {
        const int n = n0 + (tid >> 6), d = tid & 63;
        const float div = expf((float)(d & ~1) * (-9.210340371976184f / 64.0f));
        const float ang = (float)n * div;
        const float pe  = (d & 1) ? cosf(ang) : sinf(ang);
        const float hv  = feat[n * HD + d] + pe;
        h0[n * HD + d] = hv;
        hrow[tid] = hv;
    }
    __syncthreads();
    if (tid < 4 * MD) {
        const int nl = tid >> 5, m = tid & 31;
        const float* wa = scr + m * WROW;          // stride 129: conflict-free
        const float* hr = hrow + nl * HD;
        float sa = 0.f, sb = bmsg[m];
#pragma unroll
        for (int c = 0; c < HD; c++) {
            const float hv = hr[c];
            sa = fmaf(hv, wa[c], sa);
            sb = fmaf(hv, wa[HD + c], sb);
        }
        const int n = n0 + nl;
        A[n * MD + m]  = sa;
        Bb[n * MD + m] = sb;
    }
}

// ---------------------------------------------------------------------------
// Pair kernel (R9 config, INSTRUMENTED): one block (512 thr = 8 waves) per
// row-pair (iA, iB = iA+N/2). Wave w owns j in [w*128, w*128+128).
// Main loop runs REPS times (opaque zero offset defeats cross-rep CSE);
// accumulators scaled by 1/REPS (exact, power of 2) -> output == R9's.
// ---------------------------------------------------------------------------
template<int LAYER1>
__global__ __launch_bounds__(BLKP) void k_pair(
    const float* __restrict__ xsrc, const float* __restrict__ Aap,
    const float* __restrict__ Bbp, const float* __restrict__ wmsg,
    const float* __restrict__ wpos, const float* __restrict__ bpos,
    float* __restrict__ xout,
    const float* __restrict__ h0, const float* __restrict__ wf,
    const float* __restrict__ bf, const float* __restrict__ wmsg2,
    const float* __restrict__ bmsg2, float* __restrict__ A2,
    float* __restrict__ B2)
{
    const int tid   = threadIdx.x;
    const int wid   = tid >> 6;         // 0..7
    const int lane  = tid & 63;
    const int jslot = lane & 7;
    const int kq    = lane >> 3;        // k = kq*4 .. kq*4+3

    __shared__ float4 rd[2 * N];        // 32 KB: rdA | rdB (contiguous scratch)
    __shared__ float  wacc[8][8];
    __shared__ float  msAl[8][MD];
    __shared__ float  msBl[8][MD];
    __shared__ float  SxL[3];
    __shared__ float  msF[2][MD];
    __shared__ float  h0r[2][HD];
    __shared__ float  h1r[2][HD];
    float4* rdA = rd;
    float4* rdB = rd + N;

    const int iA = blockIdx.x, iB = blockIdx.x + N / 2;
    const float xiA0 = xsrc[iA * 3 + 0], xiA1 = xsrc[iA * 3 + 1], xiA2 = xsrc[iA * 3 + 2];
    const float xiB0 = xsrc[iB * 3 + 0], xiB1 = xsrc[iB * 3 + 1], xiB2 = xsrc[iB * 3 + 2];

    // ---- stage r/d2 tables for both rows; accumulate column-sum of x ----
    float sx0 = 0.f, sx1 = 0.f, sx2 = 0.f;
#pragma unroll
    for (int q = 0; q < N / BLKP; q++) {
        const int j = q * BLKP + tid;
        const float xj0 = xsrc[j * 3 + 0];
        const float xj1 = xsrc[j * 3 + 1];
        const float xj2 = xsrc[j * 3 + 2];
        sx0 += xj0; sx1 += xj1; sx2 += xj2;
        float r0 = xj0 - xiA0, r1 = xj1 - xiA1, r2 = xj2 - xiA2;
        rdA[j] = make_float4(r0, r1, r2, fmaf(r0, r0, fmaf(r1, r1, r2 * r2)));
        r0 = xj0 - xiB0; r1 = xj1 - xiB1; r2 = xj2 - xiB2;
        rdB[j] = make_float4(r0, r1, r2, fmaf(r0, r0, fmaf(r1, r1, r2 * r2)));
    }
#pragma unroll
    for (int off = 32; off > 0; off >>= 1) {
        sx0 += __shfl_xor(sx0, off);
        sx1 += __shfl_xor(sx1, off);
        sx2 += __shfl_xor(sx2, off);
    }
    if (lane == 0) { wacc[wid][0] = sx0; wacc[wid][1] = sx1; wacc[wid][2] = sx2; }
    __syncthreads();                       // rd tables + sx partials ready
    if (tid == 0) {
        float s0 = 0.f, s1 = 0.f, s2 = 0.f;
#pragma unroll
        for (int w = 0; w < 8; w++) { s0 += wacc[w][0]; s1 += wacc[w][1]; s2 += wacc[w][2]; }
        SxL[0] = s0; SxL[1] = s1; SxL[2] = s2;
    }

    // ---- per-lane weights for the 4 owned k's ----
    const float4 biA4 = *(const float4*)(Bbp + iA * MD + kq * 4);
    const float4 biB4 = *(const float4*)(Bbp + iB * MD + kq * 4);
    const float4 wpx4 = *(const float4*)(wpos + kq * 4);
    const float4 wpy4 = *(const float4*)(wpos + MD + kq * 4);
    const float4 wpz4 = *(const float4*)(wpos + 2 * MD + kq * 4);
    float wd4[4];
#pragma unroll
    for (int kk = 0; kk < 4; kk++) wd4[kk] = wmsg[(kq * 4 + kk) * WROW + 2 * HD];
    const float biA[4] = {biA4.x, biA4.y, biA4.z, biA4.w};
    const float biB[4] = {biB4.x, biB4.y, biB4.z, biB4.w};
    const float wpx[4] = {wpx4.x, wpx4.y, wpx4.z, wpx4.w};
    const float wpy[4] = {wpy4.x, wpy4.y, wpy4.z, wpy4.w};
    const float wpz[4] = {wpz4.x, wpz4.y, wpz4.z, wpz4.w};

    float PAx[4] = {0,0,0,0}, PAy[4] = {0,0,0,0}, PAz[4] = {0,0,0,0};
    float PBx[4] = {0,0,0,0}, PBy[4] = {0,0,0,0}, PBz[4] = {0,0,0,0};
    float msA[4] = {0,0,0,0}, msB[4] = {0,0,0,0};

    const int jb = wid * (N / 8);          // 128 j per wave
#pragma unroll 1
    for (int rep = 0; rep < REPS; rep++) {
        int zoff = 0;
        asm volatile("" : "+v"(zoff));     // opaque 0: defeats cross-rep CSE/hoist
#pragma unroll 8
        for (int it = 0; it < N / 8 / 8; it++) {
            const int j = jb + it * 8 + jslot + zoff;
            const float4 a4 = *(const float4*)(Aap + j * MD + kq * 4);
            const float4 fA = rdA[j];      // 8-way broadcast per address
            const float4 fB = rdB[j];
            const float av[4] = {a4.x, a4.y, a4.z, a4.w};
#pragma unroll
            for (int kk = 0; kk < 4; kk++) {
                const float mA = fmaxf(fmaf(fA.w, wd4[kk], av[kk] + biA[kk]), 0.f);
                const float mB = fmaxf(fmaf(fB.w, wd4[kk], av[kk] + biB[kk]), 0.f);
                if (LAYER1) { msA[kk] += mA; msB[kk] += mB; }
                PAx[kk] = fmaf(mA, fA.x, PAx[kk]);
                PAy[kk] = fmaf(mA, fA.y, PAy[kk]);
                PAz[kk] = fmaf(mA, fA.z, PAz[kk]);
                PBx[kk] = fmaf(mB, fB.x, PBx[kk]);
                PBy[kk] = fmaf(mB, fB.y, PBy[kk]);
                PBz[kk] = fmaf(mB, fB.z, PBz[kk]);
            }
        }
    }
    {   // scale back by 1/REPS (8 = 2^3: exact)
        const float sc = 1.0f / (float)REPS;
#pragma unroll
        for (int kk = 0; kk < 4; kk++) {
            PAx[kk] *= sc; PAy[kk] *= sc; PAz[kk] *= sc;
            PBx[kk] *= sc; PBy[kk] *= sc; PBz[kk] *= sc;
            if (LAYER1) { msA[kk] *= sc; msB[kk] *= sc; }
        }
    }

    // ---- fold wp per lane, then reduce across 64 lanes ----
    float vA0 = 0.f, vA1 = 0.f, vA2 = 0.f, vB0 = 0.f, vB1 = 0.f, vB2 = 0.f;
#pragma unroll
    for (int kk = 0; kk < 4; kk++) {
        vA0 = fmaf(PAx[kk], wpx[kk], vA0);
        vA1 = fmaf(PAy[kk], wpy[kk], vA1);
        vA2 = fmaf(PAz[kk], wpz[kk], vA2);
        vB0 = fmaf(PBx[kk], wpx[kk], vB0);
        vB1 = fmaf(PBy[kk], wpy[kk], vB1);
        vB2 = fmaf(PBz[kk], wpz[kk], vB2);
    }
#pragma unroll
    for (int off = 32; off > 0; off >>= 1) {
        vA0 += __shfl_xor(vA0, off); vA1 += __shfl_xor(vA1, off); vA2 += __shfl_xor(vA2, off);
        vB0 += __shfl_xor(vB0, off); vB1 += __shfl_xor(vB1, off); vB2 += __shfl_xor(vB2, off);
    }
    if (LAYER1) {
        // reduce msum over the 8 jslots (lane bits 0..2)
#pragma unroll
        for (int off = 1; off <= 4; off <<= 1) {
#pragma unroll
            for (int kk = 0; kk < 4; kk++) {
                msA[kk] += __shfl_xor(msA[kk], off);
                msB[kk] += __shfl_xor(msB[kk], off);
            }
        }
    }
    __syncthreads();                       // wacc consumed into SxL; reusable
    if (lane == 0) {
        wacc[wid][0] = vA0; wacc[wid][1] = vA1; wacc[wid][2] = vA2;
        wacc[wid][3] = vB0; wacc[wid][4] = vB1; wacc[wid][5] = vB2;
    }
    if (LAYER1 && jslot == 0) {
#pragma unroll
        for (int kk = 0; kk < 4; kk++) {
            msAl[wid][kq * 4 + kk] = msA[kk];
            msBl[wid][kq * 4 + kk] = msB[kk];
        }
    }
    __syncthreads();                       // epilogue data ready

    if (tid == 0) {
        const float bp0 = bpos[0], bp1 = bpos[1], bp2 = bpos[2];
        float aA0 = 0.f, aA1 = 0.f, aA2 = 0.f, aB0 = 0.f, aB1 = 0.f, aB2 = 0.f;
#pragma unroll
        for (int w = 0; w < 8; w++) {
            aA0 += wacc[w][0]; aA1 += wacc[w][1]; aA2 += wacc[w][2];
            aB0 += wacc[w][3]; aB1 += wacc[w][4]; aB2 += wacc[w][5];
        }
        const float inv = 1.0f / 1023.0f;
        xout[iA * 3 + 0] = xiA0 + (aA0 + bp0 * (SxL[0] - (float)N * xiA0)) * inv;
        xout[iA * 3 + 1] = xiA1 + (aA1 + bp1 * (SxL[1] - (float)N * xiA1)) * inv;
        xout[iA * 3 + 2] = xiA2 + (aA2 + bp2 * (SxL[2] - (float)N * xiA2)) * inv;
        xout[iB * 3 + 0] = xiB0 + (aB0 + bp0 * (SxL[0] - (float)N * xiB0)) * inv;
        xout[iB * 3 + 1] = xiB1 + (aB1 + bp1 * (SxL[1] - (float)N * xiB1)) * inv;
        xout[iB * 3 + 2] = xiB2 + (aB2 + bp2 * (SxL[2] - (float)N * xiB2)) * inv;
    }

    if (LAYER1) {
        // ---- fused h-update + layer-2 A/B projections for rows iA, iB ----
        float* scr = (float*)rd;           // 8192 floats free after main loop
        if (tid < 2 * MD) {                // msum rows with diagonal correction
            const int row = tid >> 5, k = tid & 31;
            const int i = row ? iB : iA;
            const float (*ml)[MD] = row ? msBl : msAl;
            float s = 0.f;
#pragma unroll
            for (int w = 0; w < 8; w++) s += ml[w][k];
            s -= fmaxf(Aap[i * MD + k] + Bbp[i * MD + k], 0.f);   // d2=0 at j==i
            msF[row][k] = s;
        }
        for (int u = tid; u < HD * (HD + MD); u += BLKP) {         // stage wf
            const int o = u / (HD + MD), c = u - o * (HD + MD);
            scr[o * 97 + c] = wf[u];
        }
        if (tid < 2 * HD) {
            const int row = tid >> 6, d = tid & 63;
            h0r[row][d] = h0[(row ? iB : iA) * HD + d];
        }
        __syncthreads();
        if (tid < 2 * HD) {                // h1 rows
            const int row = tid >> 6, o = tid & 63;
            const float* w = scr + o * 97;
            float s = bf[o];
#pragma unroll
            for (int c = 0; c < HD; c++) s = fmaf(h0r[row][c], w[c], s);
#pragma unroll
            for (int k = 0; k < MD; k++) s = fmaf(msF[row][k], w[HD + k], s);
            h1r[row][o] = fmaxf(s, 0.f);
        }
        __syncthreads();
        for (int u = tid; u < MD * WROW; u += BLKP) scr[u] = wmsg2[u];
        __syncthreads();
        if (tid < 2 * MD) {                // A2/B2 rows
            const int row = tid >> 5, m = tid & 31;
            const float* wa = scr + m * WROW;
            const float* hr = h1r[row];
            float sa = 0.f, sb = bmsg2[m];
#pragma unroll
            for (int c = 0; c < HD; c++) {
                const float hv = hr[c];
                sa = fmaf(hv, wa[c], sa);
                sb = fmaf(hv, wa[HD + c], sb);
            }
            const int i = row ? iB : iA;
            A2[i * MD + m] = sa;
            B2[i * MD + m] = sb;
        }
    }
}

// ---------------------------------------------------------------------------
extern "C" void kernel_launch(void* const* d_in, const int* in_sizes, int n_in,
                              void* d_out, int out_size, void* d_ws, size_t ws_size,
                              hipStream_t stream)
{
    const float* pos     = (const float*)d_in[0];
    const float* feat    = (const float*)d_in[1];
    const float* w_msg1  = (const float*)d_in[3];
    const float* b_msg1  = (const float*)d_in[4];
    const float* w_pos1  = (const float*)d_in[5];
    const float* b_pos1  = (const float*)d_in[6];
    const float* w_feat1 = (const float*)d_in[7];
    const float* b_feat1 = (const float*)d_in[8];
    const float* w_msg2  = (const float*)d_in[9];
    const float* b_msg2  = (const float*)d_in[10];
    const float* w_pos2  = (const float*)d_in[11];
    const float* b_pos2  = (const float*)d_in[12];

    float* ws  = (float*)d_ws;
    float* h0  = ws;                 // N*HD
    float* A1  = h0  + N * HD;       // N*MD
    float* B1  = A1  + N * MD;
    float* x1  = B1  + N * MD;       // N*4 (padded)
    float* A2  = x1  + N * 4;
    float* B2  = A2  + N * MD;

    k_p0<<<N / 4, BLK, 0, stream>>>(feat, w_msg1, b_msg1, h0, A1, B1);
    k_pair<1><<<N / 2, BLKP, 0, stream>>>(pos, A1, B1, w_msg1, w_pos1, b_pos1, x1,
                                          h0, w_feat1, b_feat1, w_msg2, b_msg2, A2, B2);
    k_pair<0><<<N / 2, BLKP, 0, stream>>>(x1, A2, B2, w_msg2, w_pos2, b_pos2,
                                          (float*)d_out,
                                          nullptr, nullptr, nullptr, nullptr,
                                          nullptr, nullptr, nullptr);
}

// Round 16
// 35.995 us; speedup vs baseline: 3.8579x; 3.8579x over previous
//
#include <hip/hip_runtime.h>

#define N    1024
#define HD   64
#define MD   32
#define BLK  256        // k_p0 block
#define BLKP 512        // pair-kernel block: 8 waves
#define WROW (2 * HD + 1)   // 129, w_msg row stride

typedef _Float16 h2 __attribute__((ext_vector_type(2)));

__device__ __forceinline__ float dot2(h2 a, h2 b, float c)
{
#if __has_builtin(__builtin_amdgcn_fdot2)
    return __builtin_amdgcn_fdot2(a, b, c, false);
#else
    return c + (float)a[0] * (float)b[0] + (float)a[1] * (float)b[1];
#endif
}
__device__ __forceinline__ h2 pack2(float x, float y)
{
    h2 r; r[0] = (_Float16)x; r[1] = (_Float16)y; return r;
}

// ---------------------------------------------------------------------------
// P0: h0 = feat + posenc; A1/B1 projections (A also in f16). 1 block / 4 rows.
// ---------------------------------------------------------------------------
__global__ __launch_bounds__(BLK) void k_p0(const float* __restrict__ feat,
                                            const float* __restrict__ wmsg,
                                            const float* __restrict__ bmsg,
                                            float* __restrict__ h0,
                                            float* __restrict__ A,
                                            float* __restrict__ Bb,
                                            _Float16* __restrict__ Ah)
{
    __shared__ float scr[4160 + 4 * HD];
    const int tid = threadIdx.x;
    const int n0  = blockIdx.x * 4;

    for (int u = tid; u < MD * WROW; u += BLK) scr[u] = wmsg[u];   // 4128 floats
    float* hrow = scr + 4160;
    {
        const int n = n0 + (tid >> 6), d = tid & 63;
        const float div = expf((float)(d & ~1) * (-9.210340371976184f / 64.0f));
        const float ang = (float)n * div;
        const float pe  = (d & 1) ? cosf(ang) : sinf(ang);
        const float hv  = feat[n * HD + d] + pe;
        h0[n * HD + d] = hv;
        hrow[tid] = hv;
    }
    __syncthreads();
    if (tid < 4 * MD) {
        const int nl = tid >> 5, m = tid & 31;
        const float* wa = scr + m * WROW;          // stride 129: conflict-free
        const float* hr = hrow + nl * HD;
        float sa = 0.f, sb = bmsg[m];
#pragma unroll
        for (int c = 0; c < HD; c++) {
            const float hv = hr[c];
            sa = fmaf(hv, wa[c], sa);
            sb = fmaf(hv, wa[HD + c], sb);
        }
        const int n = n0 + nl;
        A[n * MD + m]  = sa;
        Bb[n * MD + m] = sb;
        Ah[n * MD + m] = (_Float16)sa;
    }
}

// ---------------------------------------------------------------------------
// Pair kernel (packed-f16 inner loop): one block (512 thr = 8 waves) per
// row-pair (iA, iB = iA+N/2). Wave w owns j in [w*128, w*128+128).
// Lane: kq = lane>>3 owns k = kq*4..+3 (2 f16x2 pairs), jslot = lane&7.
// m2 = pk_max(pk_fma(d2_2, wd_2, pk_add(a_2, bi_2)), 0)      [1 instr / 2 k]
// s_c = v_dot2_f32_f16(m2, wp_c2, s_c)  (f32 accumulate)     [wp folded in-loop]
// acc_c += s_c * r_c ;  msum: packed-f16 accumulate (16 adds/lane, exact-safe)
// x_out[i] = x[i] + (acc_c + bp_c (Sx_c - N x_ic)) / (N-1)
// LAYER1: fused msum(diag-corrected f32)/h1/A2/B2 tail as before; A2 also f16.
// ---------------------------------------------------------------------------
template<int LAYER1>
__global__ __launch_bounds__(BLKP) void k_pair(
    const float* __restrict__ xsrc, const float* __restrict__ Aap,
    const _Float16* __restrict__ Ahp, const float* __restrict__ Bbp,
    const float* __restrict__ wmsg, const float* __restrict__ wpos,
    const float* __restrict__ bpos, float* __restrict__ xout,
    const float* __restrict__ h0, const float* __restrict__ wf,
    const float* __restrict__ bf, const float* __restrict__ wmsg2,
    const float* __restrict__ bmsg2, float* __restrict__ A2,
    float* __restrict__ B2, _Float16* __restrict__ A2h)
{
    const int tid   = threadIdx.x;
    const int wid   = tid >> 6;         // 0..7
    const int lane  = tid & 63;
    const int jslot = lane & 7;
    const int kq    = lane >> 3;        // k = kq*4 .. kq*4+3

    __shared__ float4 rd[2 * N];        // 32 KB: rdA | rdB (contiguous scratch)
    __shared__ float  wacc[8][8];
    __shared__ float  msAl[8][MD];
    __shared__ float  msBl[8][MD];
    __shared__ float  SxL[3];
    __shared__ float  msF[2][MD];
    __shared__ float  h0r[2][HD];
    __shared__ float  h1r[2][HD];
    float4* rdA = rd;
    float4* rdB = rd + N;

    const int iA = blockIdx.x, iB = blockIdx.x + N / 2;
    const float xiA0 = xsrc[iA * 3 + 0], xiA1 = xsrc[iA * 3 + 1], xiA2 = xsrc[iA * 3 + 2];
    const float xiB0 = xsrc[iB * 3 + 0], xiB1 = xsrc[iB * 3 + 1], xiB2 = xsrc[iB * 3 + 2];

    // ---- stage r/d2 tables (d2 pre-packed as f16x2 in .w); Sx partial ----
    float sx0 = 0.f, sx1 = 0.f, sx2 = 0.f;
#pragma unroll
    for (int q = 0; q < N / BLKP; q++) {
        const int j = q * BLKP + tid;
        const float xj0 = xsrc[j * 3 + 0];
        const float xj1 = xsrc[j * 3 + 1];
        const float xj2 = xsrc[j * 3 + 2];
        sx0 += xj0; sx1 += xj1; sx2 += xj2;
        float r0 = xj0 - xiA0, r1 = xj1 - xiA1, r2 = xj2 - xiA2;
        float d2 = fmaf(r0, r0, fmaf(r1, r1, r2 * r2));
        rdA[j] = make_float4(r0, r1, r2, __builtin_bit_cast(float, pack2(d2, d2)));
        r0 = xj0 - xiB0; r1 = xj1 - xiB1; r2 = xj2 - xiB2;
        d2 = fmaf(r0, r0, fmaf(r1, r1, r2 * r2));
        rdB[j] = make_float4(r0, r1, r2, __builtin_bit_cast(float, pack2(d2, d2)));
    }
#pragma unroll
    for (int off = 32; off > 0; off >>= 1) {
        sx0 += __shfl_xor(sx0, off);
        sx1 += __shfl_xor(sx1, off);
        sx2 += __shfl_xor(sx2, off);
    }
    if (lane == 0) { wacc[wid][0] = sx0; wacc[wid][1] = sx1; wacc[wid][2] = sx2; }
    __syncthreads();                       // rd tables + sx partials ready
    if (tid == 0) {
        float s0 = 0.f, s1 = 0.f, s2 = 0.f;
#pragma unroll
        for (int w = 0; w < 8; w++) { s0 += wacc[w][0]; s1 += wacc[w][1]; s2 += wacc[w][2]; }
        SxL[0] = s0; SxL[1] = s1; SxL[2] = s2;
    }

    // ---- per-lane packed weights for the 4 owned k's ----
    const float4 biA4 = *(const float4*)(Bbp + iA * MD + kq * 4);
    const float4 biB4 = *(const float4*)(Bbp + iB * MD + kq * 4);
    const float4 wpx4 = *(const float4*)(wpos + kq * 4);
    const float4 wpy4 = *(const float4*)(wpos + MD + kq * 4);
    const float4 wpz4 = *(const float4*)(wpos + 2 * MD + kq * 4);
    const h2 biA01 = pack2(biA4.x, biA4.y), biA23 = pack2(biA4.z, biA4.w);
    const h2 biB01 = pack2(biB4.x, biB4.y), biB23 = pack2(biB4.z, biB4.w);
    const h2 wpx01 = pack2(wpx4.x, wpx4.y), wpx23 = pack2(wpx4.z, wpx4.w);
    const h2 wpy01 = pack2(wpy4.x, wpy4.y), wpy23 = pack2(wpy4.z, wpy4.w);
    const h2 wpz01 = pack2(wpz4.x, wpz4.y), wpz23 = pack2(wpz4.z, wpz4.w);
    const h2 wd01 = pack2(wmsg[(kq * 4 + 0) * WROW + 2 * HD],
                          wmsg[(kq * 4 + 1) * WROW + 2 * HD]);
    const h2 wd23 = pack2(wmsg[(kq * 4 + 2) * WROW + 2 * HD],
                          wmsg[(kq * 4 + 3) * WROW + 2 * HD]);
    const h2 hz = pack2(0.f, 0.f);

    float aA0 = 0.f, aA1 = 0.f, aA2 = 0.f, aB0 = 0.f, aB1 = 0.f, aB2 = 0.f;
    h2 msA01 = hz, msA23 = hz, msB01 = hz, msB23 = hz;

    const int jb = wid * (N / 8);          // 128 j per wave
#pragma unroll 8
    for (int it = 0; it < N / 8 / 8; it++) {
        const int j = jb + it * 8 + jslot;
        const uint2 au = *(const uint2*)(Ahp + j * MD + kq * 4);  // 4 f16 = 8B/lane
        const h2 a01 = __builtin_bit_cast(h2, au.x);
        const h2 a23 = __builtin_bit_cast(h2, au.y);
        const float4 fA = rdA[j];          // 8-way broadcast per address
        const float4 fB = rdB[j];
        const h2 d2A = __builtin_bit_cast(h2, fA.w);
        const h2 d2B = __builtin_bit_cast(h2, fB.w);

        const h2 mA01 = __builtin_elementwise_max(d2A * wd01 + (a01 + biA01), hz);
        const h2 mA23 = __builtin_elementwise_max(d2A * wd23 + (a23 + biA23), hz);
        const h2 mB01 = __builtin_elementwise_max(d2B * wd01 + (a01 + biB01), hz);
        const h2 mB23 = __builtin_elementwise_max(d2B * wd23 + (a23 + biB23), hz);
        if (LAYER1) { msA01 += mA01; msA23 += mA23; msB01 += mB01; msB23 += mB23; }

        const float sAx = dot2(mA23, wpx23, dot2(mA01, wpx01, 0.f));
        const float sAy = dot2(mA23, wpy23, dot2(mA01, wpy01, 0.f));
        const float sAz = dot2(mA23, wpz23, dot2(mA01, wpz01, 0.f));
        const float sBx = dot2(mB23, wpx23, dot2(mB01, wpx01, 0.f));
        const float sBy = dot2(mB23, wpy23, dot2(mB01, wpy01, 0.f));
        const float sBz = dot2(mB23, wpz23, dot2(mB01, wpz01, 0.f));
        aA0 = fmaf(sAx, fA.x, aA0);
        aA1 = fmaf(sAy, fA.y, aA1);
        aA2 = fmaf(sAz, fA.z, aA2);
        aB0 = fmaf(sBx, fB.x, aB0);
        aB1 = fmaf(sBy, fB.y, aB1);
        aB2 = fmaf(sBz, fB.z, aB2);
    }

    // ---- reduce acc across 64 lanes (sums jslot and kq partials) ----
#pragma unroll
    for (int off = 32; off > 0; off >>= 1) {
        aA0 += __shfl_xor(aA0, off); aA1 += __shfl_xor(aA1, off); aA2 += __shfl_xor(aA2, off);
        aB0 += __shfl_xor(aB0, off); aB1 += __shfl_xor(aB1, off); aB2 += __shfl_xor(aB2, off);
    }
    float msAf[4], msBf[4];
    if (LAYER1) {
        msAf[0] = (float)msA01[0]; msAf[1] = (float)msA01[1];
        msAf[2] = (float)msA23[0]; msAf[3] = (float)msA23[1];
        msBf[0] = (float)msB01[0]; msBf[1] = (float)msB01[1];
        msBf[2] = (float)msB23[0]; msBf[3] = (float)msB23[1];
        // reduce msum over the 8 jslots (lane bits 0..2)
#pragma unroll
        for (int off = 1; off <= 4; off <<= 1) {
#pragma unroll
            for (int kk = 0; kk < 4; kk++) {
                msAf[kk] += __shfl_xor(msAf[kk], off);
                msBf[kk] += __shfl_xor(msBf[kk], off);
            }
        }
    }
    __syncthreads();                       // wacc consumed into SxL; reusable
    if (lane == 0) {
        wacc[wid][0] = aA0; wacc[wid][1] = aA1; wacc[wid][2] = aA2;
        wacc[wid][3] = aB0; wacc[wid][4] = aB1; wacc[wid][5] = aB2;
    }
    if (LAYER1 && jslot == 0) {
#pragma unroll
        for (int kk = 0; kk < 4; kk++) {
            msAl[wid][kq * 4 + kk] = msAf[kk];
            msBl[wid][kq * 4 + kk] = msBf[kk];
        }
    }
    __syncthreads();                       // epilogue data ready

    if (tid == 0) {
        const float bp0 = bpos[0], bp1 = bpos[1], bp2 = bpos[2];
        float vA0 = 0.f, vA1 = 0.f, vA2 = 0.f, vB0 = 0.f, vB1 = 0.f, vB2 = 0.f;
#pragma unroll
        for (int w = 0; w < 8; w++) {
            vA0 += wacc[w][0]; vA1 += wacc[w][1]; vA2 += wacc[w][2];
            vB0 += wacc[w][3]; vB1 += wacc[w][4]; vB2 += wacc[w][5];
        }
        const float inv = 1.0f / 1023.0f;
        xout[iA * 3 + 0] = xiA0 + (vA0 + bp0 * (SxL[0] - (float)N * xiA0)) * inv;
        xout[iA * 3 + 1] = xiA1 + (vA1 + bp1 * (SxL[1] - (float)N * xiA1)) * inv;
        xout[iA * 3 + 2] = xiA2 + (vA2 + bp2 * (SxL[2] - (float)N * xiA2)) * inv;
        xout[iB * 3 + 0] = xiB0 + (vB0 + bp0 * (SxL[0] - (float)N * xiB0)) * inv;
        xout[iB * 3 + 1] = xiB1 + (vB1 + bp1 * (SxL[1] - (float)N * xiB1)) * inv;
        xout[iB * 3 + 2] = xiB2 + (vB2 + bp2 * (SxL[2] - (float)N * xiB2)) * inv;
    }

    if (LAYER1) {
        // ---- fused h-update + layer-2 A/B projections for rows iA, iB ----
        float* scr = (float*)rd;           // 8192 floats free after main loop
        if (tid < 2 * MD) {                // msum rows with diagonal correction
            const int row = tid >> 5, k = tid & 31;
            const int i = row ? iB : iA;
            const float (*ml)[MD] = row ? msBl : msAl;
            float s = 0.f;
#pragma unroll
            for (int w = 0; w < 8; w++) s += ml[w][k];
            s -= fmaxf(Aap[i * MD + k] + Bbp[i * MD + k], 0.f);   // d2=0 at j==i
            msF[row][k] = s;
        }
        for (int u = tid; u < HD * (HD + MD); u += BLKP) {         // stage wf
            const int o = u / (HD + MD), c = u - o * (HD + MD);
            scr[o * 97 + c] = wf[u];
        }
        if (tid < 2 * HD) {
            const int row = tid >> 6, d = tid & 63;
            h0r[row][d] = h0[(row ? iB : iA) * HD + d];
        }
        __syncthreads();
        if (tid < 2 * HD) {                // h1 rows
            const int row = tid >> 6, o = tid & 63;
            const float* w = scr + o * 97;
            float s = bf[o];
#pragma unroll
            for (int c = 0; c < HD; c++) s = fmaf(h0r[row][c], w[c], s);
#pragma unroll
            for (int k = 0; k < MD; k++) s = fmaf(msF[row][k], w[HD + k], s);
            h1r[row][o] = fmaxf(s, 0.f);
        }
        __syncthreads();
        for (int u = tid; u < MD * WROW; u += BLKP) scr[u] = wmsg2[u];
        __syncthreads();
        if (tid < 2 * MD) {                // A2/B2 rows (+ f16 copy of A2)
            const int row = tid >> 5, m = tid & 31;
            const float* wa = scr + m * WROW;
            const float* hr = h1r[row];
            float sa = 0.f, sb = bmsg2[m];
#pragma unroll
            for (int c = 0; c < HD; c++) {
                const float hv = hr[c];
                sa = fmaf(hv, wa[c], sa);
                sb = fmaf(hv, wa[HD + c], sb);
            }
            const int i = row ? iB : iA;
            A2[i * MD + m]  = sa;
            B2[i * MD + m]  = sb;
            A2h[i * MD + m] = (_Float16)sa;
        }
    }
}

// ---------------------------------------------------------------------------
extern "C" void kernel_launch(void* const* d_in, const int* in_sizes, int n_in,
                              void* d_out, int out_size, void* d_ws, size_t ws_size,
                              hipStream_t stream)
{
    const float* pos     = (const float*)d_in[0];
    const float* feat    = (const float*)d_in[1];
    const float* w_msg1  = (const float*)d_in[3];
    const float* b_msg1  = (const float*)d_in[4];
    const float* w_pos1  = (const float*)d_in[5];
    const float* b_pos1  = (const float*)d_in[6];
    const float* w_feat1 = (const float*)d_in[7];
    const float* b_feat1 = (const float*)d_in[8];
    const float* w_msg2  = (const float*)d_in[9];
    const float* b_msg2  = (const float*)d_in[10];
    const float* w_pos2  = (const float*)d_in[11];
    const float* b_pos2  = (const float*)d_in[12];

    float* ws  = (float*)d_ws;
    float* h0  = ws;                 // N*HD
    float* A1  = h0  + N * HD;       // N*MD
    float* B1  = A1  + N * MD;
    float* x1  = B1  + N * MD;       // N*4 (padded)
    float* A2  = x1  + N * 4;
    float* B2  = A2  + N * MD;
    _Float16* Ah1 = (_Float16*)(B2 + N * MD);      // N*MD f16
    _Float16* Ah2 = Ah1 + N * MD;                  // N*MD f16

    k_p0<<<N / 4, BLK, 0, stream>>>(feat, w_msg1, b_msg1, h0, A1, B1, Ah1);
    k_pair<1><<<N / 2, BLKP, 0, stream>>>(pos, A1, Ah1, B1, w_msg1, w_pos1, b_pos1, x1,
                                          h0, w_feat1, b_feat1, w_msg2, b_msg2,
                                          A2, B2, Ah2);
    k_pair<0><<<N / 2, BLKP, 0, stream>>>(x1, A2, Ah2, B2, w_msg2, w_pos2, b_pos2,
                                          (float*)d_out,
                                          nullptr, nullptr, nullptr, nullptr,
                                          nullptr, nullptr, nullptr, nullptr);
}

// Round 20
// 33.730 us; speedup vs baseline: 4.1170x; 1.0672x over previous
//
#include <hip/hip_runtime.h>

#define N    1024
#define HD   64
#define MD   32
#define BLK  256        // k_p0 block
#define BLKP 512        // pair-kernel block: 8 waves
#define WROW (2 * HD + 1)   // 129, w_msg row stride

typedef _Float16 h2 __attribute__((ext_vector_type(2)));

__device__ __forceinline__ float dot2(h2 a, h2 b, float c)
{
#if __has_builtin(__builtin_amdgcn_fdot2)
    return __builtin_amdgcn_fdot2(a, b, c, false);
#else
    return c + (float)a[0] * (float)b[0] + (float)a[1] * (float)b[1];
#endif
}
__device__ __forceinline__ h2 pack2(float x, float y)
{
    h2 r; r[0] = (_Float16)x; r[1] = (_Float16)y; return r;
}

// ---------------------------------------------------------------------------
// P0: h0 = feat + posenc; A1/B1 projections (A also in f16). 1 block / 4 rows.
// ---------------------------------------------------------------------------
__global__ __launch_bounds__(BLK) void k_p0(const float* __restrict__ feat,
                                            const float* __restrict__ wmsg,
                                            const float* __restrict__ bmsg,
                                            float* __restrict__ h0,
                                            float* __restrict__ A,
                                            float* __restrict__ Bb,
                                            _Float16* __restrict__ Ah)
{
    __shared__ float scr[4160 + 4 * HD];
    const int tid = threadIdx.x;
    const int n0  = blockIdx.x * 4;

    for (int u = tid; u < MD * WROW; u += BLK) scr[u] = wmsg[u];   // 4128 floats
    float* hrow = scr + 4160;
    {
        const int n = n0 + (tid >> 6), d = tid & 63;
        const float div = expf((float)(d & ~1) * (-9.210340371976184f / 64.0f));
        const float ang = (float)n * div;
        const float pe  = (d & 1) ? cosf(ang) : sinf(ang);
        const float hv  = feat[n * HD + d] + pe;
        h0[n * HD + d] = hv;
        hrow[tid] = hv;
    }
    __syncthreads();
    if (tid < 4 * MD) {
        const int nl = tid >> 5, m = tid & 31;
        const float* wa = scr + m * WROW;          // stride 129: conflict-free
        const float* hr = hrow + nl * HD;
        float sa = 0.f, sb = bmsg[m];
#pragma unroll
        for (int c = 0; c < HD; c++) {
            const float hv = hr[c];
            sa = fmaf(hv, wa[c], sa);
            sb = fmaf(hv, wa[HD + c], sb);
        }
        const int n = n0 + nl;
        A[n * MD + m]  = sa;
        Bb[n * MD + m] = sb;
        Ah[n * MD + m] = (_Float16)sa;
    }
}

// ---------------------------------------------------------------------------
// Pair kernel v2 (tail fixed): one block (512 thr = 8 waves) per row-pair.
// SINGLE rd table: rd[j] = (rA0, rA1, rA2, pack2(d2A, d2B));
// rB reconstructed in-loop: rB = rA + (xiA - xiB).
// Lane map: kq = lane&3 owns k = kq*8..+7 (one uint4 A-load);
// jslot = lane>>2 (16 j per wave-iter) -> 8 main-loop iterations.
// Shared buffer sbuf (6848 floats) aliases BOTH rd (first 4096 floats as
// float4[N]) and the LAYER1 tail scratch (stride-97 wf stage = 6208 floats,
// wmsg2 stage = 4128 floats) -- tail identical to the verified R16 version.
// ---------------------------------------------------------------------------
template<int LAYER1>
__global__ __launch_bounds__(BLKP) void k_pair(
    const float* __restrict__ xsrc, const float* __restrict__ Aap,
    const _Float16* __restrict__ Ahp, const float* __restrict__ Bbp,
    const float* __restrict__ wmsg, const float* __restrict__ wpos,
    const float* __restrict__ bpos, float* __restrict__ xout,
    const float* __restrict__ h0, const float* __restrict__ wf,
    const float* __restrict__ bf, const float* __restrict__ wmsg2,
    const float* __restrict__ bmsg2, float* __restrict__ A2,
    float* __restrict__ B2, _Float16* __restrict__ A2h)
{
    const int tid   = threadIdx.x;
    const int wid   = tid >> 6;         // 0..7
    const int lane  = tid & 63;
    const int kq    = lane & 3;         // owns k = kq*8 .. kq*8+7
    const int jslot = lane >> 2;        // 0..15

    __shared__ float  sbuf[6848];       // 27.4 KB: rd[N] (16 KB) | tail scr
    __shared__ float  wacc[8][8];
    __shared__ float  msAl[8][MD];
    __shared__ float  msBl[8][MD];
    __shared__ float  SxL[3];
    __shared__ float  msF[2][MD];
    __shared__ float  h0r[2][HD];
    __shared__ float  h1r[2][HD];
    float4* rd = (float4*)sbuf;

    const int iA = blockIdx.x, iB = blockIdx.x + N / 2;
    const float xiA0 = xsrc[iA * 3 + 0], xiA1 = xsrc[iA * 3 + 1], xiA2 = xsrc[iA * 3 + 2];
    const float xiB0 = xsrc[iB * 3 + 0], xiB1 = xsrc[iB * 3 + 1], xiB2 = xsrc[iB * 3 + 2];
    const float dx0 = xiA0 - xiB0, dx1 = xiA1 - xiB1, dx2 = xiA2 - xiB2;  // rB = rA + dx

    // ---- stage single rd table (rA + packed d2A,d2B); Sx partial ----
    float sx0 = 0.f, sx1 = 0.f, sx2 = 0.f;
#pragma unroll
    for (int q = 0; q < N / BLKP; q++) {
        const int j = q * BLKP + tid;
        const float xj0 = xsrc[j * 3 + 0];
        const float xj1 = xsrc[j * 3 + 1];
        const float xj2 = xsrc[j * 3 + 2];
        sx0 += xj0; sx1 += xj1; sx2 += xj2;
        const float a0 = xj0 - xiA0, a1 = xj1 - xiA1, a2 = xj2 - xiA2;
        const float d2A = fmaf(a0, a0, fmaf(a1, a1, a2 * a2));
        const float b0 = xj0 - xiB0, b1 = xj1 - xiB1, b2 = xj2 - xiB2;
        const float d2B = fmaf(b0, b0, fmaf(b1, b1, b2 * b2));
        rd[j] = make_float4(a0, a1, a2, __builtin_bit_cast(float, pack2(d2A, d2B)));
    }
#pragma unroll
    for (int off = 32; off > 0; off >>= 1) {
        sx0 += __shfl_xor(sx0, off);
        sx1 += __shfl_xor(sx1, off);
        sx2 += __shfl_xor(sx2, off);
    }
    if (lane == 0) { wacc[wid][0] = sx0; wacc[wid][1] = sx1; wacc[wid][2] = sx2; }
    __syncthreads();                       // rd table + sx partials ready
    if (tid == 0) {
        float s0 = 0.f, s1 = 0.f, s2 = 0.f;
#pragma unroll
        for (int w = 0; w < 8; w++) { s0 += wacc[w][0]; s1 += wacc[w][1]; s2 += wacc[w][2]; }
        SxL[0] = s0; SxL[1] = s1; SxL[2] = s2;
    }

    // ---- per-lane packed weights for the 8 owned k's ----
    h2 biA[4], biB[4], wpx[4], wpy[4], wpz[4], wd[4];
    {
        const float4 bA0 = *(const float4*)(Bbp + iA * MD + kq * 8);
        const float4 bA1 = *(const float4*)(Bbp + iA * MD + kq * 8 + 4);
        const float4 bB0 = *(const float4*)(Bbp + iB * MD + kq * 8);
        const float4 bB1 = *(const float4*)(Bbp + iB * MD + kq * 8 + 4);
        biA[0] = pack2(bA0.x, bA0.y); biA[1] = pack2(bA0.z, bA0.w);
        biA[2] = pack2(bA1.x, bA1.y); biA[3] = pack2(bA1.z, bA1.w);
        biB[0] = pack2(bB0.x, bB0.y); biB[1] = pack2(bB0.z, bB0.w);
        biB[2] = pack2(bB1.x, bB1.y); biB[3] = pack2(bB1.z, bB1.w);
        const float4 px0 = *(const float4*)(wpos + kq * 8);
        const float4 px1 = *(const float4*)(wpos + kq * 8 + 4);
        const float4 py0 = *(const float4*)(wpos + MD + kq * 8);
        const float4 py1 = *(const float4*)(wpos + MD + kq * 8 + 4);
        const float4 pz0 = *(const float4*)(wpos + 2 * MD + kq * 8);
        const float4 pz1 = *(const float4*)(wpos + 2 * MD + kq * 8 + 4);
        wpx[0] = pack2(px0.x, px0.y); wpx[1] = pack2(px0.z, px0.w);
        wpx[2] = pack2(px1.x, px1.y); wpx[3] = pack2(px1.z, px1.w);
        wpy[0] = pack2(py0.x, py0.y); wpy[1] = pack2(py0.z, py0.w);
        wpy[2] = pack2(py1.x, py1.y); wpy[3] = pack2(py1.z, py1.w);
        wpz[0] = pack2(pz0.x, pz0.y); wpz[1] = pack2(pz0.z, pz0.w);
        wpz[2] = pack2(pz1.x, pz1.y); wpz[3] = pack2(pz1.z, pz1.w);
#pragma unroll
        for (int t = 0; t < 4; t++)
            wd[t] = pack2(wmsg[(kq * 8 + 2 * t) * WROW + 2 * HD],
                          wmsg[(kq * 8 + 2 * t + 1) * WROW + 2 * HD]);
    }
    const h2 hz = pack2(0.f, 0.f);

    float aA0 = 0.f, aA1 = 0.f, aA2 = 0.f, aB0 = 0.f, aB1 = 0.f, aB2 = 0.f;
    h2 msA[4] = {hz, hz, hz, hz}, msB[4] = {hz, hz, hz, hz};

    const int jb = wid * (N / 8);          // 128 j per wave
#pragma unroll 8
    for (int it = 0; it < 8; it++) {
        const int j = jb + it * 16 + jslot;
        const uint4 au = *(const uint4*)(Ahp + j * MD + kq * 8);  // 8 f16 = 16B/lane
        h2 a[4];
        a[0] = __builtin_bit_cast(h2, au.x); a[1] = __builtin_bit_cast(h2, au.y);
        a[2] = __builtin_bit_cast(h2, au.z); a[3] = __builtin_bit_cast(h2, au.w);
        const float4 f = rd[j];            // 4-way broadcast per address
        const h2 dd = __builtin_bit_cast(h2, f.w);
        const h2 dA = __builtin_shufflevector(dd, dd, 0, 0);   // op_sel splat
        const h2 dB = __builtin_shufflevector(dd, dd, 1, 1);
        const float rB0 = f.x + dx0, rB1 = f.y + dx1, rB2 = f.z + dx2;

        h2 mA[4], mB[4];
#pragma unroll
        for (int t = 0; t < 4; t++) {
            mA[t] = __builtin_elementwise_max(dA * wd[t] + (a[t] + biA[t]), hz);
            mB[t] = __builtin_elementwise_max(dB * wd[t] + (a[t] + biB[t]), hz);
            if (LAYER1) { msA[t] += mA[t]; msB[t] += mB[t]; }
        }
        const float sAx = dot2(mA[3], wpx[3], dot2(mA[2], wpx[2], dot2(mA[1], wpx[1], dot2(mA[0], wpx[0], 0.f))));
        const float sAy = dot2(mA[3], wpy[3], dot2(mA[2], wpy[2], dot2(mA[1], wpy[1], dot2(mA[0], wpy[0], 0.f))));
        const float sAz = dot2(mA[3], wpz[3], dot2(mA[2], wpz[2], dot2(mA[1], wpz[1], dot2(mA[0], wpz[0], 0.f))));
        const float sBx = dot2(mB[3], wpx[3], dot2(mB[2], wpx[2], dot2(mB[1], wpx[1], dot2(mB[0], wpx[0], 0.f))));
        const float sBy = dot2(mB[3], wpy[3], dot2(mB[2], wpy[2], dot2(mB[1], wpy[1], dot2(mB[0], wpy[0], 0.f))));
        const float sBz = dot2(mB[3], wpz[3], dot2(mB[2], wpz[2], dot2(mB[1], wpz[1], dot2(mB[0], wpz[0], 0.f))));
        aA0 = fmaf(sAx, f.x, aA0);
        aA1 = fmaf(sAy, f.y, aA1);
        aA2 = fmaf(sAz, f.z, aA2);
        aB0 = fmaf(sBx, rB0, aB0);
        aB1 = fmaf(sBy, rB1, aB1);
        aB2 = fmaf(sBz, rB2, aB2);
    }

    // ---- reduce acc across 64 lanes (sums jslot and kq partials) ----
#pragma unroll
    for (int off = 32; off > 0; off >>= 1) {
        aA0 += __shfl_xor(aA0, off); aA1 += __shfl_xor(aA1, off); aA2 += __shfl_xor(aA2, off);
        aB0 += __shfl_xor(aB0, off); aB1 += __shfl_xor(aB1, off); aB2 += __shfl_xor(aB2, off);
    }
    float msAf[8], msBf[8];
    if (LAYER1) {
#pragma unroll
        for (int t = 0; t < 4; t++) {
            msAf[2 * t] = (float)msA[t][0]; msAf[2 * t + 1] = (float)msA[t][1];
            msBf[2 * t] = (float)msB[t][0]; msBf[2 * t + 1] = (float)msB[t][1];
        }
        // reduce msum over the 16 jslots (lane bits 2..5)
#pragma unroll
        for (int off = 4; off <= 32; off <<= 1) {
#pragma unroll
            for (int t = 0; t < 8; t++) {
                msAf[t] += __shfl_xor(msAf[t], off);
                msBf[t] += __shfl_xor(msBf[t], off);
            }
        }
    }
    __syncthreads();                       // wacc consumed into SxL; reusable
    if (lane == 0) {
        wacc[wid][0] = aA0; wacc[wid][1] = aA1; wacc[wid][2] = aA2;
        wacc[wid][3] = aB0; wacc[wid][4] = aB1; wacc[wid][5] = aB2;
    }
    if (LAYER1 && jslot == 0) {            // lanes 0..3, one per kq
#pragma unroll
        for (int t = 0; t < 8; t++) {
            msAl[wid][kq * 8 + t] = msAf[t];
            msBl[wid][kq * 8 + t] = msBf[t];
        }
    }
    __syncthreads();                       // epilogue data ready

    if (tid == 0) {
        const float bp0 = bpos[0], bp1 = bpos[1], bp2 = bpos[2];
        float vA0 = 0.f, vA1 = 0.f, vA2 = 0.f, vB0 = 0.f, vB1 = 0.f, vB2 = 0.f;
#pragma unroll
        for (int w = 0; w < 8; w++) {
            vA0 += wacc[w][0]; vA1 += wacc[w][1]; vA2 += wacc[w][2];
            vB0 += wacc[w][3]; vB1 += wacc[w][4]; vB2 += wacc[w][5];
        }
        const float inv = 1.0f / 1023.0f;
        xout[iA * 3 + 0] = xiA0 + (vA0 + bp0 * (SxL[0] - (float)N * xiA0)) * inv;
        xout[iA * 3 + 1] = xiA1 + (vA1 + bp1 * (SxL[1] - (float)N * xiA1)) * inv;
        xout[iA * 3 + 2] = xiA2 + (vA2 + bp2 * (SxL[2] - (float)N * xiA2)) * inv;
        xout[iB * 3 + 0] = xiB0 + (vB0 + bp0 * (SxL[0] - (float)N * xiB0)) * inv;
        xout[iB * 3 + 1] = xiB1 + (vB1 + bp1 * (SxL[1] - (float)N * xiB1)) * inv;
        xout[iB * 3 + 2] = xiB2 + (vB2 + bp2 * (SxL[2] - (float)N * xiB2)) * inv;
    }

    if (LAYER1) {
        // ---- fused h-update + layer-2 A/B projections (R16-verified tail) ----
        float* scr = sbuf;                 // 6848 floats free after main loop
        if (tid < 2 * MD) {                // msum rows with diagonal correction
            const int row = tid >> 5, k = tid & 31;
            const int i = row ? iB : iA;
            const float (*ml)[MD] = row ? msBl : msAl;
            float s = 0.f;
#pragma unroll
            for (int w = 0; w < 8; w++) s += ml[w][k];
            s -= fmaxf(Aap[i * MD + k] + Bbp[i * MD + k], 0.f);   // d2=0 at j==i
            msF[row][k] = s;
        }
        for (int u = tid; u < HD * (HD + MD); u += BLKP) {         // stage wf
            const int o = u / (HD + MD), c = u - o * (HD + MD);
            scr[o * 97 + c] = wf[u];       // max 63*97+95 = 6206 < 6848
        }
        if (tid < 2 * HD) {
            const int row = tid >> 6, d = tid & 63;
            h0r[row][d] = h0[(row ? iB : iA) * HD + d];
        }
        __syncthreads();
        if (tid < 2 * HD) {                // h1 rows (all 64 outputs)
            const int row = tid >> 6, o = tid & 63;
            const float* w = scr + o * 97;
            float s = bf[o];
#pragma unroll
            for (int c = 0; c < HD; c++) s = fmaf(h0r[row][c], w[c], s);
#pragma unroll
            for (int k = 0; k < MD; k++) s = fmaf(msF[row][k], w[HD + k], s);
            h1r[row][o] = fmaxf(s, 0.f);
        }
        __syncthreads();
        for (int u = tid; u < MD * WROW; u += BLKP) scr[u] = wmsg2[u];  // 4128 < 6848
        __syncthreads();
        if (tid < 2 * MD) {                // A2/B2 rows (+ f16 copy of A2)
            const int row = tid >> 5, m = tid & 31;
            const float* wa = scr + m * WROW;
            const float* hr = h1r[row];
            float sa = 0.f, sb = bmsg2[m];
#pragma unroll
            for (int c = 0; c < HD; c++) {
                const float hv = hr[c];
                sa = fmaf(hv, wa[c], sa);
                sb = fmaf(hv, wa[HD + c], sb);
            }
            const int i = row ? iB : iA;
            A2[i * MD + m]  = sa;
            B2[i * MD + m]  = sb;
            A2h[i * MD + m] = (_Float16)sa;
        }
    }
}

// ---------------------------------------------------------------------------
extern "C" void kernel_launch(void* const* d_in, const int* in_sizes, int n_in,
                              void* d_out, int out_size, void* d_ws, size_t ws_size,
                              hipStream_t stream)
{
    const float* pos     = (const float*)d_in[0];
    const float* feat    = (const float*)d_in[1];
    const float* w_msg1  = (const float*)d_in[3];
    const float* b_msg1  = (const float*)d_in[4];
    const float* w_pos1  = (const float*)d_in[5];
    const float* b_pos1  = (const float*)d_in[6];
    const float* w_feat1 = (const float*)d_in[7];
    const float* b_feat1 = (const float*)d_in[8];
    const float* w_msg2  = (const float*)d_in[9];
    const float* b_msg2  = (const float*)d_in[10];
    const float* w_pos2  = (const float*)d_in[11];
    const float* b_pos2  = (const float*)d_in[12];

    float* ws  = (float*)d_ws;
    float* h0  = ws;                 // N*HD
    float* A1  = h0  + N * HD;       // N*MD
    float* B1  = A1  + N * MD;
    float* x1  = B1  + N * MD;       // N*4 (padded)
    float* A2  = x1  + N * 4;
    float* B2  = A2  + N * MD;
    _Float16* Ah1 = (_Float16*)(B2 + N * MD);      // N*MD f16
    _Float16* Ah2 = Ah1 + N * MD;                  // N*MD f16

    k_p0<<<N / 4, BLK, 0, stream>>>(feat, w_msg1, b_msg1, h0, A1, B1, Ah1);
    k_pair<1><<<N / 2, BLKP, 0, stream>>>(pos, A1, Ah1, B1, w_msg1, w_pos1, b_pos1, x1,
                                          h0, w_feat1, b_feat1, w_msg2, b_msg2,
                                          A2, B2, Ah2);
    k_pair<0><<<N / 2, BLKP, 0, stream>>>(x1, A2, Ah2, B2, w_msg2, w_pos2, b_pos2,
                                          (float*)d_out,
                                          nullptr, nullptr, nullptr, nullptr,
                                          nullptr, nullptr, nullptr, nullptr);
}